// Round 1
// baseline (513.883 us; speedup 1.0000x reference)
//
#include <hip/hip_runtime.h>
#include <cstdint>
#include <cstddef>

#define BB 64
#define HH 168
#define NN 512
#define FF 8
#define UL 128   // lstm units
#define GD 512   // gate dim (4*UL)

__device__ __forceinline__ float sigf(float x){ return 1.0f/(1.0f+__expf(-x)); }
// tanh via exp2-based expf; exact at saturation (exp->inf => 1, exp->0 => -1)
__device__ __forceinline__ float tanhfast(float x){ return 1.0f - 2.0f/(1.0f+__expf(2.0f*x)); }

// ---------------- summaries: partial sums over half the H axis ----------------
// grid 256: b = bid>>2, nh = (bid>>1)&1, hh = bid&1 ; block 256
__global__ __launch_bounds__(256) void k_sum(const float* __restrict__ in, float* __restrict__ ps){
  int bid = blockIdx.x;
  int b = bid>>2, nh = (bid>>1)&1, hh = bid&1;
  int n = nh*256 + threadIdx.x;
  int h0 = hh*84;
  const float* p = in + ((size_t)(b*HH + h0)*NN + n)*FF;
  float s1=0.f,s2=0.f,s3=0.f,s4=0.f,st=0.f;
  #pragma unroll 4
  for(int h=0;h<84;++h){
    float x = p[(size_t)h*NN*FF];
    float hc = (float)(h+h0) - 83.5f;
    s1 += x;
    float x2 = x*x;
    s2 += x2;
    s3 += x2*x;
    s4 += x2*x2;
    st += hc*x;
  }
  float* o = ps + ((size_t)((b*NN+n)*2 + hh))*8;
  o[0]=s1; o[1]=s2; o[2]=s3; o[3]=s4; o[4]=st;
}

// combine partials -> nf[b,n,7]
// grid 128, block 256 (exactly 32768 = B*N threads)
__global__ __launch_bounds__(256) void k_sumc(const float* __restrict__ ps, float* __restrict__ nf){
  int idx = blockIdx.x*256 + threadIdx.x;
  const float* a = ps + (size_t)idx*16;
  const float* c2 = a + 8;
  float s1 = a[0]+c2[0], s2 = a[1]+c2[1], s3 = a[2]+c2[2], s4 = a[3]+c2[3], st = a[4]+c2[4];
  float s1h = c2[0], s2h = c2[1];
  const float iH = 1.0f/168.0f, iHh = 1.0f/84.0f;
  float mean = s1*iH, meanh = s1h*iHh;
  float ex2 = s2*iH, ex3 = s3*iH, ex4 = s4*iH;
  float m2 = ex2 - mean*mean;
  float m3 = ex3 - 3.0f*mean*ex2 + 2.0f*mean*mean*mean;
  float m4 = ex4 - 4.0f*mean*ex3 + 6.0f*mean*mean*ex2 - 3.0f*mean*mean*mean*mean;
  m2 = fmaxf(m2, 0.0f);
  float stdf = sqrtf(m2);
  float m2h = fmaxf(s2h*iHh - meanh*meanh, 0.0f);
  float stdh = sqrtf(m2h);
  float denom = m2*stdf;
  float skew = denom > 0.0f ? m3/denom : 0.0f;
  float kurt = m2 > 0.0f ? (m4/(m2*m2) - 3.0f) : 0.0f;
  float slope = st * (1.0f/395122.0f);  // sum((h-83.5)^2, h<168) = 395122 exactly
  float* o = nf + (size_t)idx*7;
  o[0]=mean; o[1]=meanh; o[2]=stdf; o[3]=stdh; o[4]=skew; o[5]=kurt; o[6]=slope;
}

// ---------------- GCN layer 1: h1 = relu(adj @ (nf@w1) + b1) ----------------
// grid 256: b = bid>>2, n0 = (bid&3)*128 ; block 256
__global__ __launch_bounds__(256) void k_gcn1(const float* __restrict__ nf, const float* __restrict__ adj,
        const float* __restrict__ w1, const float* __restrict__ b1, float* __restrict__ h1){
  __shared__ float t_s[NN*32];       // 64KB: t = nf@w1 for this b
  __shared__ float adj_s[128*68];    // 34KB: padded (+4) adj tile
  int b = blockIdx.x>>2, n0 = (blockIdx.x&3)*128;
  int tid = threadIdx.x;

  // stage t
  {
    int c = tid&31;
    float w1c[7];
    #pragma unroll
    for(int k=0;k<7;++k) w1c[k] = w1[k*32+c];
    for(int idx=tid; idx<NN*32; idx+=256){
      int m = idx>>5;
      const float* nfp = nf + (size_t)(b*NN+m)*7;
      float acc = 0.f;
      #pragma unroll
      for(int k=0;k<7;++k) acc += nfp[k]*w1c[k];
      t_s[idx] = acc;
    }
  }
  int c2 = tid&15, nl = tid>>4;       // thread owns c = 2*c2, 2*c2+1 ; rows n0+nl+16*j
  float acc[8][2];
  #pragma unroll
  for(int j=0;j<8;++j){acc[j][0]=0.f;acc[j][1]=0.f;}
  for(int mt=0; mt<8; ++mt){
    __syncthreads();
    for(int idx=tid; idx<128*64; idx+=256){
      int r = idx>>6, cc = idx&63;
      adj_s[r*68+cc] = adj[(size_t)(n0+r)*NN + mt*64 + cc];
    }
    __syncthreads();
    for(int mm=0; mm<64; mm+=4){
      float2 tv[4];
      #pragma unroll
      for(int q=0;q<4;++q) tv[q] = *(const float2*)&t_s[(mt*64+mm+q)*32 + 2*c2];
      #pragma unroll
      for(int j=0;j<8;++j){
        float4 a4 = *(const float4*)&adj_s[(nl+16*j)*68 + mm];
        acc[j][0] += a4.x*tv[0].x + a4.y*tv[1].x + a4.z*tv[2].x + a4.w*tv[3].x;
        acc[j][1] += a4.x*tv[0].y + a4.y*tv[1].y + a4.z*tv[2].y + a4.w*tv[3].y;
      }
    }
  }
  float bb0 = b1[2*c2], bb1 = b1[2*c2+1];
  #pragma unroll
  for(int j=0;j<8;++j){
    int n = n0 + nl + 16*j;
    float2 v;
    v.x = fmaxf(acc[j][0]+bb0, 0.0f);
    v.y = fmaxf(acc[j][1]+bb1, 0.0f);
    *(float2*)&h1[(size_t)(b*NN+n)*32 + 2*c2] = v;
  }
}

// ---------------- GCN layer 2: g = relu(adj @ (h1@w2) + b2) ----------------
// grid 256: b = bid>>2, n0 = (bid&3)*128 ; block 256
__global__ __launch_bounds__(256) void k_gcn2(const float* __restrict__ h1, const float* __restrict__ adj,
        const float* __restrict__ w2, const float* __restrict__ b2, float* __restrict__ g){
  __shared__ float t_s[NN*16];       // 32KB: t2 = h1@w2
  __shared__ float adj_s[128*68];    // 34KB
  int b = blockIdx.x>>2, n0 = (blockIdx.x&3)*128;
  int tid = threadIdx.x;
  // stage t2: thread owns output cols 2*jh, 2*jh+1 (jh invariant under idx+=256)
  {
    int jh = tid&7;
    float w2c0[32], w2c1[32];
    #pragma unroll
    for(int c=0;c<32;++c){ w2c0[c] = w2[c*16+2*jh]; w2c1[c] = w2[c*16+2*jh+1]; }
    for(int idx=tid; idx<NN*8; idx+=256){
      int m = idx>>3;
      const float4* hp = (const float4*)(h1 + (size_t)(b*NN+m)*32);
      float a0=0.f, a1=0.f;
      #pragma unroll
      for(int q=0;q<8;++q){
        float4 hv = hp[q];
        a0 += hv.x*w2c0[4*q] + hv.y*w2c0[4*q+1] + hv.z*w2c0[4*q+2] + hv.w*w2c0[4*q+3];
        a1 += hv.x*w2c1[4*q] + hv.y*w2c1[4*q+1] + hv.z*w2c1[4*q+2] + hv.w*w2c1[4*q+3];
      }
      t_s[m*16+2*jh] = a0;
      t_s[m*16+2*jh+1] = a1;
    }
  }
  int j = tid&15, nl = tid>>4;   // rows n0+nl+16*q
  float acc[8];
  #pragma unroll
  for(int q=0;q<8;++q) acc[q]=0.f;
  for(int mt=0; mt<8; ++mt){
    __syncthreads();
    for(int idx=tid; idx<128*64; idx+=256){
      int r = idx>>6, cc = idx&63;
      adj_s[r*68+cc] = adj[(size_t)(n0+r)*NN + mt*64 + cc];
    }
    __syncthreads();
    for(int mm=0; mm<64; mm+=4){
      float tv[4];
      #pragma unroll
      for(int q=0;q<4;++q) tv[q] = t_s[(mt*64+mm+q)*16 + j];
      #pragma unroll
      for(int q=0;q<8;++q){
        float4 a4 = *(const float4*)&adj_s[(nl+16*q)*68 + mm];
        acc[q] += a4.x*tv[0] + a4.y*tv[1] + a4.z*tv[2] + a4.w*tv[3];
      }
    }
  }
  float bbj = b2[j];
  #pragma unroll
  for(int q=0;q<8;++q){
    int n = n0 + nl + 16*q;
    g[(size_t)(b*NN+n)*16 + j] = fmaxf(acc[q]+bbj, 0.0f);
  }
}

// ---------------- conv1 -> pool -> conv2 -> feat[b, 0:64] ----------------
// grid 64, block 64
__global__ __launch_bounds__(64) void k_conv(const float* __restrict__ g, const float* __restrict__ wc1,
        const float* __restrict__ bc1, const float* __restrict__ wc2, const float* __restrict__ bc2,
        float* __restrict__ feat){
  __shared__ float g_s[NN*16];   // 32KB
  __shared__ float c1_s[4][16];
  __shared__ float p_s[4][8];
  int b = blockIdx.x, tid = threadIdx.x;
  for(int idx=tid; idx<NN*16; idx+=64) g_s[idx] = g[(size_t)b*NN*16 + idx];
  __syncthreads();
  {
    int o = tid>>4, x = tid&15;
    float acc = bc1[o];
    for(int k=0;k<3;++k){
      int xx = x + k - 1;
      if(xx>=0 && xx<16){
        for(int c=0;c<NN;++c) acc += g_s[c*16+xx]*wc1[(size_t)(k*NN+c)*4+o];
      }
    }
    c1_s[o][x] = acc;
  }
  __syncthreads();
  if(tid<32){
    int oo = tid>>3, xp = tid&7;
    float pv = 0.5f*(c1_s[oo][2*xp]+c1_s[oo][2*xp+1]);
    p_s[oo][xp] = pv;
    feat[b*192 + 32 + oo*8 + xp] = pv;
  }
  __syncthreads();
  if(tid<32){
    int oo = tid>>3, x2 = tid&7;
    float a2 = bc2[oo];
    #pragma unroll
    for(int k=0;k<3;++k){
      int xx = x2 + k - 1;
      if(xx>=0 && xx<8){
        #pragma unroll
        for(int c=0;c<4;++c) a2 += p_s[c][xx]*wc2[(k*4+c)*4+oo];
      }
    }
    feat[b*192 + oo*8 + x2] = a2;
  }
}

// ---------------- LSTM1 recurrence: l1[b,t,u] ----------------
// grid 64 (one block per batch), block 512 (one thread per gate column)
__global__ __launch_bounds__(512) void k_lstm1(const float* __restrict__ in, const float* __restrict__ k1,
        const float* __restrict__ rk1, const float* __restrict__ b1, float* __restrict__ l1){
  __shared__ float seq_s[HH*FF];   // 1344 floats
  __shared__ float h_s[UL];
  __shared__ float a_s[GD];
  int b = blockIdx.x, u = threadIdx.x;
  float wk[FF], wr[UL];
  #pragma unroll
  for(int f=0;f<FF;++f) wk[f] = k1[f*GD+u];
  #pragma unroll
  for(int j=0;j<UL;++j) wr[j] = rk1[j*GD+u];
  float bz = b1[u];
  for(int idx=u; idx<HH*FF; idx+=GD)
    seq_s[idx] = in[(size_t)(b*HH + (idx>>3))*NN*FF + (idx&7)];
  if(u<UL) h_s[u]=0.0f;
  float c = 0.0f;
  __syncthreads();
  int gate = u>>7;
  for(int t=0;t<HH;++t){
    float z0 = bz, z1 = 0.f, z2 = 0.f, z3 = 0.f;
    #pragma unroll
    for(int f=0;f<FF;f+=2){ z0 += seq_s[t*FF+f]*wk[f]; z1 += seq_s[t*FF+f+1]*wk[f+1]; }
    const float4* h4 = (const float4*)h_s;
    #pragma unroll
    for(int q=0;q<UL/4;++q){
      float4 hv = h4[q];
      z0 += hv.x*wr[4*q];
      z1 += hv.y*wr[4*q+1];
      z2 += hv.z*wr[4*q+2];
      z3 += hv.w*wr[4*q+3];
    }
    float z = (z0+z1)+(z2+z3);
    a_s[u] = (gate==2) ? tanhfast(z) : sigf(z);
    __syncthreads();
    if(u<UL){
      float ia = a_s[u], fa = a_s[UL+u], ga = a_s[2*UL+u], oa = a_s[3*UL+u];
      c = fa*c + ia*ga;
      float hn = oa*tanhfast(c);
      h_s[u] = hn;
      l1[((size_t)b*HH + t)*UL + u] = hn;
    }
    __syncthreads();
  }
}

// ---------------- zin2 = l1 @ k2 + b2  (non-recurrent, all 256 CUs) ----------------
// grid 512: b = bid>>3, t0 = (bid&7)*21 ; block 256
__global__ __launch_bounds__(256) void k_zin2(const float* __restrict__ l1, const float* __restrict__ k2,
        const float* __restrict__ b2, float* __restrict__ zin){
  __shared__ float l_s[21*UL];   // 10.5KB
  int b = blockIdx.x>>3, t0 = (blockIdx.x&7)*21;
  int tid = threadIdx.x;
  for(int idx=tid; idx<21*UL; idx+=256)
    l_s[idx] = l1[((size_t)b*HH + t0 + (idx>>7))*UL + (idx&127)];
  __syncthreads();
  float acc0[21], acc1[21];
  #pragma unroll
  for(int q=0;q<21;++q){acc0[q]=0.f;acc1[q]=0.f;}
  for(int j=0;j<UL;++j){
    float kv0 = k2[j*GD + tid];
    float kv1 = k2[j*GD + tid + 256];
    #pragma unroll
    for(int q=0;q<21;++q){
      float lv = l_s[q*UL + j];
      acc0[q] += lv*kv0;
      acc1[q] += lv*kv1;
    }
  }
  float bb0 = b2[tid], bb1 = b2[tid+256];
  #pragma unroll
  for(int q=0;q<21;++q){
    zin[((size_t)b*HH + t0 + q)*GD + tid]       = acc0[q] + bb0;
    zin[((size_t)b*HH + t0 + q)*GD + tid + 256] = acc1[q] + bb1;
  }
}

// ---------------- LSTM2 recurrence: feat[b, 64:192] = last h ----------------
// grid 64, block 512
__global__ __launch_bounds__(512) void k_lstm2(const float* __restrict__ zin, const float* __restrict__ rk2,
        float* __restrict__ feat){
  __shared__ float h_s[UL];
  __shared__ float a_s[GD];
  int b = blockIdx.x, u = threadIdx.x;
  float wr[UL];
  #pragma unroll
  for(int j=0;j<UL;++j) wr[j] = rk2[j*GD+u];
  if(u<UL) h_s[u]=0.0f;
  float c = 0.0f;
  __syncthreads();
  int gate = u>>7;
  for(int t=0;t<HH;++t){
    float z0 = zin[((size_t)b*HH+t)*GD + u], z1 = 0.f, z2 = 0.f, z3 = 0.f;
    const float4* h4 = (const float4*)h_s;
    #pragma unroll
    for(int q=0;q<UL/4;++q){
      float4 hv = h4[q];
      z0 += hv.x*wr[4*q];
      z1 += hv.y*wr[4*q+1];
      z2 += hv.z*wr[4*q+2];
      z3 += hv.w*wr[4*q+3];
    }
    float z = (z0+z1)+(z2+z3);
    a_s[u] = (gate==2) ? tanhfast(z) : sigf(z);
    __syncthreads();
    if(u<UL){
      float ia = a_s[u], fa = a_s[UL+u], ga = a_s[2*UL+u], oa = a_s[3*UL+u];
      c = fa*c + ia*ga;
      float hn = oa*tanhfast(c);
      h_s[u] = hn;
      if(t==HH-1) feat[b*192 + 64 + u] = hn;
    }
    __syncthreads();
  }
}

// ---------------- final dense: out = feat @ w_out + b_out ----------------
// grid 6, block 256 (1536 = 64*24 outputs)
__global__ __launch_bounds__(256) void k_out(const float* __restrict__ feat, const float* __restrict__ wo,
        const float* __restrict__ bo, float* __restrict__ out){
  int idx = blockIdx.x*256 + threadIdx.x;
  if(idx >= BB*24) return;
  int b = idx/24, p = idx - b*24;
  float a0 = bo[p], a1 = 0.f, a2 = 0.f, a3 = 0.f;
  const float* f = feat + b*192;
  for(int k=0;k<192;k+=4){
    a0 += f[k]*wo[k*24+p];
    a1 += f[k+1]*wo[(k+1)*24+p];
    a2 += f[k+2]*wo[(k+2)*24+p];
    a3 += f[k+3]*wo[(k+3)*24+p];
  }
  out[idx] = (a0+a1)+(a2+a3);
}

extern "C" void kernel_launch(void* const* d_in, const int* in_sizes, int n_in,
                              void* d_out, int out_size, void* d_ws, size_t ws_size,
                              hipStream_t stream){
  const float* inp = (const float*)d_in[0];
  const float* adj = (const float*)d_in[1];
  const float* w1  = (const float*)d_in[2];
  const float* b1  = (const float*)d_in[3];
  const float* w2  = (const float*)d_in[4];
  const float* b2  = (const float*)d_in[5];
  const float* wc1 = (const float*)d_in[6];
  const float* bc1 = (const float*)d_in[7];
  const float* wc2 = (const float*)d_in[8];
  const float* bc2 = (const float*)d_in[9];
  const float* k1  = (const float*)d_in[10];
  const float* rk1 = (const float*)d_in[11];
  const float* bl1 = (const float*)d_in[12];
  const float* k2  = (const float*)d_in[13];
  const float* rk2 = (const float*)d_in[14];
  const float* bl2 = (const float*)d_in[15];
  const float* wo  = (const float*)d_in[16];
  const float* bo  = (const float*)d_in[17];
  float* out = (float*)d_out;
  float* ws = (float*)d_ws;

  float* ps   = ws;                 // 64*512*2*8   = 524288
  float* nf   = ps + 524288;        // 64*512*7     = 229376
  float* h1   = nf + 229376;        // 64*512*32    = 1048576
  float* g    = h1 + 1048576;       // 64*512*16    = 524288
  float* feat = g  + 524288;        // 64*192       = 12288
  float* l1   = feat + 12288;       // 64*168*128   = 1376256
  float* zin  = l1 + 1376256;       // 64*168*512   = 5505024  (total ~35.2 MB)

  k_sum  <<<dim3(256), dim3(256), 0, stream>>>(inp, ps);
  k_sumc <<<dim3(128), dim3(256), 0, stream>>>(ps, nf);
  k_gcn1 <<<dim3(256), dim3(256), 0, stream>>>(nf, adj, w1, b1, h1);
  k_gcn2 <<<dim3(256), dim3(256), 0, stream>>>(h1, adj, w2, b2, g);
  k_conv <<<dim3(64),  dim3(64),  0, stream>>>(g, wc1, bc1, wc2, bc2, feat);
  k_lstm1<<<dim3(64),  dim3(512), 0, stream>>>(inp, k1, rk1, bl1, l1);
  k_zin2 <<<dim3(512), dim3(256), 0, stream>>>(l1, k2, bl2, zin);
  k_lstm2<<<dim3(64),  dim3(512), 0, stream>>>(zin, rk2, feat);
  k_out  <<<dim3(6),   dim3(256), 0, stream>>>(feat, wo, bo, out);
}